// Round 2
// baseline (225.264 us; speedup 1.0000x reference)
//
#include <hip/hip_runtime.h>

#define TOTAL 4146
#define TLEN  4096
#define BURN  50

// One thread per series (4096 series). Serial over time; histories live in
// registers via rotating constant indices (fully unrolled), noise prefetched
// triple-buffered 96 steps ahead (~1600 cy cover vs ~900 cy HBM latency,
// needed since 1 wave/SIMD => no TLP), cumsum (d levels) fused branchlessly
// as two gated accumulators.
__global__ __launch_bounds__(64) void arima_kernel(
    const float* __restrict__ phi_,
    const float* __restrict__ theta_,
    const float* __restrict__ icept_,
    const float* __restrict__ sigma_,
    const float* __restrict__ noise_,
    const int*   __restrict__ dvals_,
    float* __restrict__ out_)
{
    const int i = blockIdx.x * blockDim.x + threadIdx.x;

    const float P0 = phi_[i*4+0], P1 = phi_[i*4+1], P2 = phi_[i*4+2], P3 = phi_[i*4+3];
    const float TH0 = theta_[i*4+0], TH1 = theta_[i*4+1], TH2 = theta_[i*4+2], TH3 = theta_[i*4+3];
    const float c  = icept_[i];
    const float sg = sigma_[i];
    const int   d  = dvals_[i];
    const float g1 = (d >= 1) ? 1.0f : 0.0f;   // cumsum level 1 gate
    const float g2 = (d >= 2) ? 1.0f : 0.0f;   // cumsum level 2 gate

    const float* __restrict__ nrow = noise_ + (size_t)i * TOTAL;
    float* __restrict__ orow = out_ + (size_t)i * TLEN;

    // rotating histories: yh = last 4 ARMA outputs, m = last 4 raw noise vals
    float yh[4] = {0.f, 0.f, 0.f, 0.f};
    float m[4]  = {0.f, 0.f, 0.f, 0.f};
    float w1 = 0.f, w2 = 0.f;                  // integration accumulators

// s must be a compile-time constant at each expansion (full unroll) so all
// array indices fold to constants -> registers (rule: runtime-indexed arrays
// go to scratch). Loop-carried dep is only yv -> P0*yv (1 FMA deep): the
// theta/partial-phi sums of step t+1 are independent of yv_t.
#define STEP_BODY(NT, s)                                \
    {                                                   \
        const float nt = (NT);                          \
        float u = fmaf(TH0, m[(s+3)&3], nt);            \
        u = fmaf(TH1, m[(s+2)&3], u);                   \
        u = fmaf(TH2, m[(s+1)&3], u);                   \
        u = fmaf(TH3, m[(s+0)&3], u);                   \
        float yv = fmaf(sg, u, c);                      \
        yv = fmaf(P3, yh[(s+0)&3], yv);                 \
        yv = fmaf(P2, yh[(s+1)&3], yv);                 \
        yv = fmaf(P1, yh[(s+2)&3], yv);                 \
        yv = fmaf(P0, yh[(s+3)&3], yv);                 \
        yh[s&3] = yv;                                   \
        m[s&3] = nt;                                    \
        w1 = fmaf(g1, w1, yv);                          \
        w2 = fmaf(g2, w2, w1);                          \
    }

    // ---- burn-in: 50 steps, all noise preloaded up front (one latency hit)
    {
        float2 bi[25];
        const float2* np2 = reinterpret_cast<const float2*>(nrow);
        #pragma unroll
        for (int k = 0; k < 25; ++k) bi[k] = np2[k];
        #pragma unroll
        for (int s = 0; s < 50; ++s) {
            const float ntv = (s & 1) ? bi[s >> 1].y : bi[s >> 1].x;
            STEP_BODY(ntv, s);
        }
        // renumber histories: burn-in ended at s=49, main loop restarts s=0.
        // main s=0 reads [3] as most-recent; after s=49 most-recent is [1]:
        // current m = {n48,n49,n46,n47}, needed {n46,n47,n48,n49}
        // -> swap pairs (0<->2),(1<->3). Same for yh.
        const float a0 = yh[0], a1 = yh[1], a2 = yh[2], a3 = yh[3];
        yh[0] = a2; yh[1] = a3; yh[2] = a0; yh[3] = a1;
        const float b0 = m[0], b1 = m[1], b2 = m[2], b3 = m[3];
        m[0] = b2; m[1] = b3; m[2] = b0; m[3] = b1;
    }

    // ---- main loop: 4096 steps = 128 phases of 32. Triple-buffered noise:
    // phase at time t consumes its buffer then refills it for t+96 (first
    // consumed 2 phases = ~1600 cy later).
    float2 bufA[16], bufB[16], bufC[16];
    {
        const float2* pa = reinterpret_cast<const float2*>(nrow + BURN);
        const float2* pb = reinterpret_cast<const float2*>(nrow + BURN + 32);
        const float2* pc = reinterpret_cast<const float2*>(nrow + BURN + 64);
        #pragma unroll
        for (int k = 0; k < 16; ++k) bufA[k] = pa[k];
        #pragma unroll
        for (int k = 0; k < 16; ++k) bufB[k] = pb[k];
        #pragma unroll
        for (int k = 0; k < 16; ++k) bufC[k] = pc[k];
    }

    float stg[4];
    int t = BURN;

#define PHASE(BUF)                                                          \
    {                                                                       \
        float4* o4 = reinterpret_cast<float4*>(orow + (t - BURN));          \
        _Pragma("unroll")                                                   \
        for (int s = 0; s < 32; ++s) {                                      \
            const float ntv = (s & 1) ? BUF[s >> 1].y : BUF[s >> 1].x;      \
            STEP_BODY(ntv, s);                                              \
            stg[s & 3] = w2;                                                \
            if ((s & 3) == 3)                                               \
                o4[s >> 2] = make_float4(stg[0], stg[1], stg[2], stg[3]);   \
        }                                                                   \
        int tt = t + 96;                                                    \
        if (tt > TOTAL - 32) tt = TOTAL - 32; /* tail: valid load, unused */\
        const float2* pp = reinterpret_cast<const float2*>(nrow + tt);      \
        _Pragma("unroll")                                                   \
        for (int k = 0; k < 16; ++k) BUF[k] = pp[k];                        \
        t += 32;                                                            \
    }

    // 128 phases = 42*(A,B,C) + A,B
    for (int it = 0; it < 42; ++it) {
        PHASE(bufA)
        PHASE(bufB)
        PHASE(bufC)
    }
    PHASE(bufA)
    PHASE(bufB)

#undef PHASE
#undef STEP_BODY
}

extern "C" void kernel_launch(void* const* d_in, const int* in_sizes, int n_in,
                              void* d_out, int out_size, void* d_ws, size_t ws_size,
                              hipStream_t stream)
{
    const float* phi   = (const float*)d_in[0];
    const float* theta = (const float*)d_in[1];
    const float* icept = (const float*)d_in[2];
    const float* sigma = (const float*)d_in[3];
    const float* noise = (const float*)d_in[4];
    const int*   dvals = (const int*)d_in[5];
    float* out = (float*)d_out;
    // 4096 series, one thread each; 64-thread blocks -> 64 waves spread over
    // distinct CUs (max per-wave issue bandwidth at this thread count).
    arima_kernel<<<dim3(4096 / 64), dim3(64), 0, stream>>>(
        phi, theta, icept, sigma, noise, dvals, out);
}